// Round 10
// baseline (330.457 us; speedup 1.0000x reference)
//
#include <hip/hip_runtime.h>
#include <math.h>

#define BB 32
#define MM 2048
#define KK 4
#define EE 128
#define GG 128
#define VV 50000
#define NT 391      // 128-row tiles over V
#define SBLK 16384  // scores_s blocks: (B*M)/4
#define VFB 6250    // vfinal blocks: B*V/256

// ---------------- GRU cell: one block per batch row; also zeroes o1 ----------------
__global__ __launch_bounds__(384) void gru_kernel(
    const float* __restrict__ emb0,   // emb table 0 [V][E]
    const int*   __restrict__ y,      // [B]
    const float* __restrict__ hprev,  // [B][G]
    const float* __restrict__ W_ih,   // [3G][E]
    const float* __restrict__ W_hh,   // [3G][G]
    const float* __restrict__ b_ih,   // [3G]
    const float* __restrict__ b_hh,   // [3G]
    float* __restrict__ h_out,        // d_out [B][G]
    float* __restrict__ q,            // ws    [B][G]
    float* __restrict__ o1)           // ws    [B][E] -> zeroed (atomics later)
{
    int b = blockIdx.x;
    int t = threadIdx.x;
    __shared__ float x[EE], h[GG], gi[3*GG], gh[3*GG];
    if (t < EE)            x[t]       = emb0[(size_t)y[b]*EE + t];
    else if (t < 2*EE)     h[t-EE]    = hprev[b*GG + (t-EE)];
    if (t < EE) o1[b*EE + t] = 0.f;
    __syncthreads();
    {
        float accI = b_ih[t], accH = b_hh[t];
        const float* wi = W_ih + (size_t)t*EE;
        const float* wh = W_hh + (size_t)t*GG;
        #pragma unroll 8
        for (int e = 0; e < EE; e++) { accI += x[e]*wi[e]; accH += h[e]*wh[e]; }
        gi[t] = accI; gh[t] = accH;
    }
    __syncthreads();
    if (t < GG) {
        float r = 1.f/(1.f + __expf(-(gi[t]        + gh[t])));
        float z = 1.f/(1.f + __expf(-(gi[GG+t]     + gh[GG+t])));
        float n = tanhf(gi[2*GG+t] + r*gh[2*GG+t]);
        float hn = (1.f - z)*n + z*h[t];
        h_out[b*GG + t] = hn;
        q[b*GG + t]     = hn;
    }
}

// ---------------- t[b][v] = emb0[v] . q[b] : dense streaming GEMM (hop 0 scores) ----
__global__ __launch_bounds__(256) void t_kernel(
    const float* __restrict__ q,      // [B][E]
    const float* __restrict__ embT,   // [V][E]
    float* __restrict__ t)            // [B][V]
{
    __shared__ float Ut[EE][32];      // q transposed [e][b]
    __shared__ float Wt[32][132];     // [e_local][v_local], pad 128->132
    int tid = threadIdx.x;
    for (int i = tid; i < EE*32; i += 256) {
        int e = i >> 5, b = i & 31;
        Ut[e][b] = q[b*EE + e];
    }
    int vg = tid & 31;
    int bg = tid >> 5;
    int v0 = blockIdx.x * 128;
    float acc[4][4];
    #pragma unroll
    for (int i = 0; i < 4; i++)
        #pragma unroll
        for (int j = 0; j < 4; j++) acc[i][j] = 0.f;

    int vrow = tid >> 1;
    int half = tid & 1;
    const float* wrow = embT + (size_t)(v0 + vrow)*EE + half*16;
    bool vok = (v0 + vrow) < VV;

    for (int ec = 0; ec < EE; ec += 32) {
        __syncthreads();
        #pragma unroll
        for (int j = 0; j < 4; j++) {
            float4 w = make_float4(0.f, 0.f, 0.f, 0.f);
            if (vok) w = *(const float4*)(wrow + ec + j*4);
            int e0 = half*16 + j*4;
            Wt[e0+0][vrow] = w.x;
            Wt[e0+1][vrow] = w.y;
            Wt[e0+2][vrow] = w.z;
            Wt[e0+3][vrow] = w.w;
        }
        __syncthreads();
        #pragma unroll 8
        for (int e = 0; e < 32; e++) {
            float4 w = *(const float4*)(&Wt[e][vg*4]);
            float4 u = *(const float4*)(&Ut[ec + e][bg*4]);
            acc[0][0] += w.x*u.x; acc[0][1] += w.x*u.y; acc[0][2] += w.x*u.z; acc[0][3] += w.x*u.w;
            acc[1][0] += w.y*u.x; acc[1][1] += w.y*u.y; acc[1][2] += w.y*u.z; acc[1][3] += w.y*u.w;
            acc[2][0] += w.z*u.x; acc[2][1] += w.z*u.y; acc[2][2] += w.z*u.z; acc[2][3] += w.z*u.w;
            acc[3][0] += w.w*u.x; acc[3][1] += w.w*u.y; acc[3][2] += w.w*u.z; acc[3][3] += w.w*u.w;
        }
    }
    #pragma unroll
    for (int i = 0; i < 4; i++) {
        int v = v0 + vg*4 + i;
        if (v < VV) {
            #pragma unroll
            for (int j = 0; j < 4; j++)
                t[(size_t)(bg*4 + j)*VV + v] = acc[i][j];
        }
    }
}

// ---------------- hop 0 scores via t-lookup: p[b][m] = sum_k t[b][ctx] ----------------
__global__ __launch_bounds__(256) void scores_lookup_kernel(
    const float* __restrict__ t,      // [B][V]
    const int*   __restrict__ ctx,    // [B][M][K]
    float* __restrict__ p)            // [B][M]
{
    int gid = blockIdx.x*256 + threadIdx.x;   // == b*M + m
    int b   = gid >> 11;
    const int4 c = *(const int4*)(ctx + (size_t)gid*KK);
    const float* tb = t + (size_t)b*VV;
    p[gid] = tb[c.x] + tb[c.y] + tb[c.z] + tb[c.w];
}

// ---------------- fused: softmax stats + weighted gather + S write + q update ----------
template<int SAVE_O1>
__global__ __launch_bounds__(256) void oacc_fused_kernel(
    const float* __restrict__ embT,   // emb + (hop+1)*V*E
    const int*   __restrict__ ctx,    // [B][M][K]
    const float* __restrict__ p,      // [B][M] raw scores
    float* __restrict__ S_out,        // [B*M][E] row sums
    float* __restrict__ q,            // [B][E] atomic +=
    float* __restrict__ o1)           // [B][E] atomic += (if SAVE_O1)
{
    int blk = blockIdx.x;             // b*32 + s
    int b = blk >> 5, s = blk & 31;
    int t = threadIdx.x;
    int w = t >> 6, lane = t & 63;

    const float* row = p + (size_t)b*MM;
    float v[8];
    float mx = -INFINITY;
    #pragma unroll
    for (int i = 0; i < 8; i++) { v[i] = row[t + i*256]; mx = fmaxf(mx, v[i]); }
    __shared__ float red[6];
    #pragma unroll
    for (int off = 32; off; off >>= 1) mx = fmaxf(mx, __shfl_down(mx, off));
    if (lane == 0) red[w] = mx;
    __syncthreads();
    if (t == 0) red[4] = fmaxf(fmaxf(red[0],red[1]), fmaxf(red[2],red[3]));
    __syncthreads();
    mx = red[4];
    float sum = 0.f;
    #pragma unroll
    for (int i = 0; i < 8; i++) sum += __expf(v[i] - mx);
    #pragma unroll
    for (int off = 32; off; off >>= 1) sum += __shfl_down(sum, off);
    __syncthreads();
    if (lane == 0) red[w] = sum;
    __syncthreads();
    if (t == 0) red[5] = 1.f / (red[0]+red[1]+red[2]+red[3]);
    __syncthreads();
    float rs = red[5];

    int m0 = s*64 + w*16;
    float ax = 0.f, ay = 0.f;
    #pragma unroll 4
    for (int i = 0; i < 16; i++) {
        int m = m0 + i;
        float a = __expf(row[m] - mx) * rs;
        const int4 c = *(const int4*)(ctx + (size_t)(b*MM + m)*KK);
        float2 v0 = *(const float2*)(embT + (size_t)c.x*EE + lane*2);
        float2 v1 = *(const float2*)(embT + (size_t)c.y*EE + lane*2);
        float2 v2 = *(const float2*)(embT + (size_t)c.z*EE + lane*2);
        float2 v3 = *(const float2*)(embT + (size_t)c.w*EE + lane*2);
        float sx = v0.x + v1.x + v2.x + v3.x;
        float sy = v0.y + v1.y + v2.y + v3.y;
        *(float2*)(S_out + ((size_t)b*MM + m)*EE + lane*2) = make_float2(sx, sy);
        ax += a * sx;
        ay += a * sy;
    }
    __shared__ float acc_red[4][EE];
    acc_red[w][lane*2]   = ax;
    acc_red[w][lane*2+1] = ay;
    __syncthreads();
    if (t < EE) {
        float vv = acc_red[0][t] + acc_red[1][t] + acc_red[2][t] + acc_red[3][t];
        atomicAdd(&q[b*EE + t], vv);
        if (SAVE_O1) atomicAdd(&o1[b*EE + t], vv);
    }
}

// ---------------- softmax over M: writes final attn output (hop 2) ----------------
__global__ __launch_bounds__(256) void softmax_m_kernel(
    const float* __restrict__ p,      // [B][M]
    float* __restrict__ attn)         // [B][M]
{
    int b = blockIdx.x, t = threadIdx.x;
    const float* row = p + (size_t)b*MM;
    float v[8];
    float mx = -INFINITY;
    #pragma unroll
    for (int i = 0; i < 8; i++) { v[i] = row[t + i*256]; mx = fmaxf(mx, v[i]); }
    __shared__ float red[6];
    int w = t >> 6, lane = t & 63;
    #pragma unroll
    for (int off = 32; off; off >>= 1) mx = fmaxf(mx, __shfl_down(mx, off));
    if (lane == 0) red[w] = mx;
    __syncthreads();
    if (t == 0) { float m2 = fmaxf(fmaxf(red[0],red[1]), fmaxf(red[2],red[3])); red[4] = m2; }
    __syncthreads();
    mx = red[4];
    float sum = 0.f;
    #pragma unroll
    for (int i = 0; i < 8; i++) { v[i] = __expf(v[i] - mx); sum += v[i]; }
    #pragma unroll
    for (int off = 32; off; off >>= 1) sum += __shfl_down(sum, off);
    if (lane == 0) red[w] = sum;
    __syncthreads();
    if (t == 0) { red[5] = 1.f / (red[0]+red[1]+red[2]+red[3]); }
    __syncthreads();
    float rs = red[5];
    #pragma unroll
    for (int i = 0; i < 8; i++) attn[(size_t)b*MM + t + i*256] = v[i]*rs;
}

// ---------------- HORIZONTAL FUSION 1: scores_s1 (blocks 0..SBLK-1) + logits GEMM ----
// Both depend only on oacc0's outputs (S1,q) / (h,o1): co-dispatch as disjoint
// block ranges. Scores blocks are BW-bound, logits blocks LDS/VALU-bound -> overlap.
__global__ __launch_bounds__(256) void sl_kernel(
    const float* __restrict__ S,      // [B*M][E]  (S1)
    const float* __restrict__ q,      // [B][E]
    float* __restrict__ p,            // [B][M]    (p1 out)
    const float* __restrict__ h,      // [B][G]
    const float* __restrict__ o1,     // [B][E]
    const float* __restrict__ Wv,     // [V][256]
    const float* __restrict__ bv,     // [V]
    float* __restrict__ logits,       // [B][V]
    float* __restrict__ part)         // [B][NT][2]
{
    __shared__ float Ut[256][32];
    __shared__ float Wt[32][132];
    int tid = threadIdx.x;
    if (blockIdx.x < SBLK) {
        // ---- scores_s body ----
        int gid  = blockIdx.x * 4 + (tid >> 6);
        int lane = tid & 63;
        int b    = gid >> 11;
        float2 sv = *(const float2*)(S + (size_t)gid*EE + lane*2);
        float2 qv = *(const float2*)(q + b*EE + lane*2);
        float acc = sv.x*qv.x + sv.y*qv.y;
        #pragma unroll
        for (int off = 32; off; off >>= 1) acc += __shfl_down(acc, off);
        if (lane == 0) p[gid] = acc;
        return;
    }
    // ---- logits GEMM body (tile index re-based) ----
    int tile = blockIdx.x - SBLK;
    for (int i = tid; i < 256*32; i += 256) {
        int e = i >> 5, b = i & 31;
        Ut[e][b] = (e < GG) ? h[b*GG + e] : o1[b*EE + (e - GG)];
    }
    int vg = tid & 31;
    int bg = tid >> 5;
    int v0 = tile * 128;
    float acc[4][4];
    #pragma unroll
    for (int i = 0; i < 4; i++)
        #pragma unroll
        for (int j = 0; j < 4; j++) acc[i][j] = 0.f;

    int vrow = tid >> 1;
    int half = tid & 1;
    const float* wrow = Wv + (size_t)(v0 + vrow)*256 + half*16;
    bool vrok = (v0 + vrow) < VV;

    for (int ec = 0; ec < 256; ec += 32) {
        __syncthreads();
        #pragma unroll
        for (int j = 0; j < 4; j++) {
            float4 w = make_float4(0.f, 0.f, 0.f, 0.f);
            if (vrok) w = *(const float4*)(wrow + ec + j*4);
            int e0 = half*16 + j*4;
            Wt[e0+0][vrow] = w.x;
            Wt[e0+1][vrow] = w.y;
            Wt[e0+2][vrow] = w.z;
            Wt[e0+3][vrow] = w.w;
        }
        __syncthreads();
        #pragma unroll 8
        for (int e = 0; e < 32; e++) {
            float4 w = *(const float4*)(&Wt[e][vg*4]);
            float4 u = *(const float4*)(&Ut[ec + e][bg*4]);
            acc[0][0] += w.x*u.x; acc[0][1] += w.x*u.y; acc[0][2] += w.x*u.z; acc[0][3] += w.x*u.w;
            acc[1][0] += w.y*u.x; acc[1][1] += w.y*u.y; acc[1][2] += w.y*u.z; acc[1][3] += w.y*u.w;
            acc[2][0] += w.z*u.x; acc[2][1] += w.z*u.y; acc[2][2] += w.z*u.z; acc[2][3] += w.z*u.w;
            acc[3][0] += w.w*u.x; acc[3][1] += w.w*u.y; acc[3][2] += w.w*u.z; acc[3][3] += w.w*u.w;
        }
    }
    #pragma unroll
    for (int i = 0; i < 4; i++) {
        int v = v0 + vg*4 + i;
        bool ok = v < VV;
        float bb = ok ? bv[v] : 0.f;
        #pragma unroll
        for (int j = 0; j < 4; j++) {
            float val = ok ? (acc[i][j] + bb) : -INFINITY;
            acc[i][j] = val;
            if (ok) logits[(size_t)(bg*4 + j)*VV + v] = val;
        }
    }
    #pragma unroll
    for (int j = 0; j < 4; j++) {
        float m = fmaxf(fmaxf(acc[0][j], acc[1][j]), fmaxf(acc[2][j], acc[3][j]));
        #pragma unroll
        for (int off = 16; off; off >>= 1) m = fmaxf(m, __shfl_down(m, off, 32));
        m = __shfl(m, 0, 32);
        float s = 0.f;
        #pragma unroll
        for (int i = 0; i < 4; i++) s += __expf(acc[i][j] - m);
        #pragma unroll
        for (int off = 16; off; off >>= 1) s += __shfl_down(s, off, 32);
        if (vg == 0) {
            int b = bg*4 + j;
            part[((size_t)b*NT + tile)*2]     = m;
            part[((size_t)b*NT + tile)*2 + 1] = s;
        }
    }
}

// ---------------- HORIZONTAL FUSION 2: scores_s2 (blocks 0..SBLK-1) + vfinal ----------
// Both depend only on oacc1 (S2,q) / sl's part (logits partials): co-dispatch.
__global__ __launch_bounds__(256) void sv_kernel(
    const float* __restrict__ S,      // [B*M][E]  (S2)
    const float* __restrict__ q,      // [B][E]
    float* __restrict__ p,            // [B][M]    (p2 out)
    float* __restrict__ logits,       // [B][V] in-place normalize
    const float* __restrict__ part)   // [B][NT][2]
{
    int tid = threadIdx.x;
    __shared__ float redm[256], reds[256];
    __shared__ float statM[2], statR[2];
    if (blockIdx.x < SBLK) {
        // ---- scores_s body ----
        int gid  = blockIdx.x * 4 + (tid >> 6);
        int lane = tid & 63;
        int b    = gid >> 11;
        float2 sv = *(const float2*)(S + (size_t)gid*EE + lane*2);
        float2 qv = *(const float2*)(q + b*EE + lane*2);
        float acc = sv.x*qv.x + sv.y*qv.y;
        #pragma unroll
        for (int off = 32; off; off >>= 1) acc += __shfl_down(acc, off);
        if (lane == 0) p[gid] = acc;
        return;
    }
    // ---- vfinal body (block index re-based) ----
    int i0  = (blockIdx.x - SBLK)*256;
    int b0  = i0 / VV;
    int last = min(i0 + 255, BB*VV - 1);
    int bL  = last / VV;
    for (int pass = 0; pass < 2; pass++) {
        int b = b0 + pass;
        if (b > bL) break;
        float m = -INFINITY, s = 0.f;
        for (int tt = tid; tt < NT; tt += 256) {
            float pm = part[((size_t)b*NT + tt)*2];
            float ps = part[((size_t)b*NT + tt)*2 + 1];
            float M2 = fmaxf(m, pm);
            s = s*__expf(m - M2) + ps*__expf(pm - M2);
            m = M2;
        }
        redm[tid] = m; reds[tid] = s;
        __syncthreads();
        for (int off = 128; off; off >>= 1) {
            if (tid < off) {
                float m2 = redm[tid+off], s2 = reds[tid+off];
                float M2 = fmaxf(redm[tid], m2);
                reds[tid] = reds[tid]*__expf(redm[tid]-M2) + s2*__expf(m2-M2);
                redm[tid] = M2;
            }
            __syncthreads();
        }
        if (tid == 0) { statM[pass] = redm[0]; statR[pass] = 1.f / reds[0]; }
        __syncthreads();
    }
    int i = i0 + tid;
    if (i < BB*VV) {
        int b = i / VV;
        int pass = b - b0;
        logits[i] = __expf(logits[i] - statM[pass]) * statR[pass];
    }
}

extern "C" void kernel_launch(void* const* d_in, const int* in_sizes, int n_in,
                              void* d_out, int out_size, void* d_ws, size_t ws_size,
                              hipStream_t stream) {
    const int*   ctx    = (const int*)  d_in[0];
    const float* h_prev = (const float*)d_in[1];
    const int*   y      = (const int*)  d_in[2];
    const float* emb    = (const float*)d_in[3];
    const float* W_ih   = (const float*)d_in[4];
    const float* W_hh   = (const float*)d_in[5];
    const float* b_ih   = (const float*)d_in[6];
    const float* b_hh   = (const float*)d_in[7];
    const float* Wv     = (const float*)d_in[8];
    const float* bv     = (const float*)d_in[9];

    float* out_h    = (float*)d_out;                 // [B][G]
    float* out_pv   = out_h + BB*GG;                 // [B][V]
    float* out_attn = out_pv + (size_t)BB*VV;        // [B][M]

    float* ws   = (float*)d_ws;
    float* q    = ws;                       // 4096
    float* o1   = q + BB*EE;                // 4096
    float* p    = o1 + BB*EE;               // 65536
    float* tbuf = p + BB*MM;                // B*V (6.4 MB)
    float* S1   = tbuf + (size_t)BB*VV;     // 33.5 MB
    float* S2   = S1 + (size_t)BB*MM*EE;    // 33.5 MB
    float* part = S2 + (size_t)BB*MM*EE;    // B*NT*2 = 25024 floats

    const float* e0 = emb;
    const float* e1 = emb + (size_t)1*VV*EE;
    const float* e2 = emb + (size_t)2*VV*EE;

    // 1. GRU -> h, q ; zero o1
    gru_kernel<<<BB, 384, 0, stream>>>(emb, y, h_prev, W_ih, W_hh, b_ih, b_hh, out_h, q, o1);

    // 2-3. hop 0 scores via t-trick
    t_kernel<<<NT, 256, 0, stream>>>(q, e0, tbuf);
    scores_lookup_kernel<<<(BB*MM)/256, 256, 0, stream>>>(tbuf, ctx, p);

    // 4. hop 0 memory read: gather table1 + write S1; q += o0, o1 = o0
    oacc_fused_kernel<1><<<BB*32, 256, 0, stream>>>(e1, ctx, p, S1, q, o1);

    // 5. FUSED: hop-1 streamed scores (S1.q) || vocab logits GEMM (h,o1) + partials
    sl_kernel<<<SBLK + NT, 256, 0, stream>>>(S1, q, p, out_h, o1, Wv, bv, out_pv, part);

    // 6. hop 1 memory read: gather table2 + write S2; q += o
    oacc_fused_kernel<0><<<BB*32, 256, 0, stream>>>(e2, ctx, p, S2, q, nullptr);

    // 7. FUSED: hop-2 streamed scores (S2.q) || vocab softmax finalize (part)
    sv_kernel<<<SBLK + VFB, 256, 0, stream>>>(S2, q, p, out_pv, part);

    // 8. attn = softmax(p2)
    softmax_m_kernel<<<BB, 256, 0, stream>>>(p, out_attn);
}

// Round 11
// 315.841 us; speedup vs baseline: 1.0463x; 1.0463x over previous
//
#include <hip/hip_runtime.h>
#include <math.h>

#define BB 32
#define MM 2048
#define KK 4
#define EE 128
#define GG 128
#define VV 50000
#define NT 391   // 128-row tiles over V
#define VFB 6250 // vfinal blocks: B*V/256

// ---------------- GRU cell: one block per batch row; also zeroes o1 ----------------
__global__ __launch_bounds__(384) void gru_kernel(
    const float* __restrict__ emb0,   // emb table 0 [V][E]
    const int*   __restrict__ y,      // [B]
    const float* __restrict__ hprev,  // [B][G]
    const float* __restrict__ W_ih,   // [3G][E]
    const float* __restrict__ W_hh,   // [3G][G]
    const float* __restrict__ b_ih,   // [3G]
    const float* __restrict__ b_hh,   // [3G]
    float* __restrict__ h_out,        // d_out [B][G]
    float* __restrict__ q,            // ws    [B][G]
    float* __restrict__ o1)           // ws    [B][E] -> zeroed (atomics later)
{
    int b = blockIdx.x;
    int t = threadIdx.x;
    __shared__ float x[EE], h[GG], gi[3*GG], gh[3*GG];
    if (t < EE)            x[t]       = emb0[(size_t)y[b]*EE + t];
    else if (t < 2*EE)     h[t-EE]    = hprev[b*GG + (t-EE)];
    if (t < EE) o1[b*EE + t] = 0.f;
    __syncthreads();
    {
        float accI = b_ih[t], accH = b_hh[t];
        const float* wi = W_ih + (size_t)t*EE;
        const float* wh = W_hh + (size_t)t*GG;
        #pragma unroll 8
        for (int e = 0; e < EE; e++) { accI += x[e]*wi[e]; accH += h[e]*wh[e]; }
        gi[t] = accI; gh[t] = accH;
    }
    __syncthreads();
    if (t < GG) {
        float r = 1.f/(1.f + __expf(-(gi[t]        + gh[t])));
        float z = 1.f/(1.f + __expf(-(gi[GG+t]     + gh[GG+t])));
        float n = tanhf(gi[2*GG+t] + r*gh[2*GG+t]);
        float hn = (1.f - z)*n + z*h[t];
        h_out[b*GG + t] = hn;
        q[b*GG + t]     = hn;
    }
}

// ---------------- t[b][v] = emb0[v] . q[b] : dense streaming GEMM (hop 0 scores) ----
__global__ __launch_bounds__(256) void t_kernel(
    const float* __restrict__ q,      // [B][E]
    const float* __restrict__ embT,   // [V][E]
    float* __restrict__ t)            // [B][V]
{
    __shared__ float Ut[EE][32];      // q transposed [e][b]
    __shared__ float Wt[32][132];     // [e_local][v_local], pad 128->132
    int tid = threadIdx.x;
    for (int i = tid; i < EE*32; i += 256) {
        int e = i >> 5, b = i & 31;
        Ut[e][b] = q[b*EE + e];
    }
    int vg = tid & 31;
    int bg = tid >> 5;
    int v0 = blockIdx.x * 128;
    float acc[4][4];
    #pragma unroll
    for (int i = 0; i < 4; i++)
        #pragma unroll
        for (int j = 0; j < 4; j++) acc[i][j] = 0.f;

    int vrow = tid >> 1;
    int half = tid & 1;
    const float* wrow = embT + (size_t)(v0 + vrow)*EE + half*16;
    bool vok = (v0 + vrow) < VV;

    for (int ec = 0; ec < EE; ec += 32) {
        __syncthreads();
        #pragma unroll
        for (int j = 0; j < 4; j++) {
            float4 w = make_float4(0.f, 0.f, 0.f, 0.f);
            if (vok) w = *(const float4*)(wrow + ec + j*4);
            int e0 = half*16 + j*4;
            Wt[e0+0][vrow] = w.x;
            Wt[e0+1][vrow] = w.y;
            Wt[e0+2][vrow] = w.z;
            Wt[e0+3][vrow] = w.w;
        }
        __syncthreads();
        #pragma unroll 8
        for (int e = 0; e < 32; e++) {
            float4 w = *(const float4*)(&Wt[e][vg*4]);
            float4 u = *(const float4*)(&Ut[ec + e][bg*4]);
            acc[0][0] += w.x*u.x; acc[0][1] += w.x*u.y; acc[0][2] += w.x*u.z; acc[0][3] += w.x*u.w;
            acc[1][0] += w.y*u.x; acc[1][1] += w.y*u.y; acc[1][2] += w.y*u.z; acc[1][3] += w.y*u.w;
            acc[2][0] += w.z*u.x; acc[2][1] += w.z*u.y; acc[2][2] += w.z*u.z; acc[2][3] += w.z*u.w;
            acc[3][0] += w.w*u.x; acc[3][1] += w.w*u.y; acc[3][2] += w.w*u.z; acc[3][3] += w.w*u.w;
        }
    }
    #pragma unroll
    for (int i = 0; i < 4; i++) {
        int v = v0 + vg*4 + i;
        if (v < VV) {
            #pragma unroll
            for (int j = 0; j < 4; j++)
                t[(size_t)(bg*4 + j)*VV + v] = acc[i][j];
        }
    }
}

// ---------------- hop 0 scores via t-lookup: p[b][m] = sum_k t[b][ctx] ----------------
__global__ __launch_bounds__(256) void scores_lookup_kernel(
    const float* __restrict__ t,      // [B][V]
    const int*   __restrict__ ctx,    // [B][M][K]
    float* __restrict__ p)            // [B][M]
{
    int gid = blockIdx.x*256 + threadIdx.x;   // == b*M + m
    int b   = gid >> 11;
    const int4 c = *(const int4*)(ctx + (size_t)gid*KK);
    const float* tb = t + (size_t)b*VV;
    p[gid] = tb[c.x] + tb[c.y] + tb[c.z] + tb[c.w];
}

// ---------------- fused: softmax stats + weighted gather + S write + q update ----------
template<int SAVE_O1>
__global__ __launch_bounds__(256) void oacc_fused_kernel(
    const float* __restrict__ embT,   // emb + (hop+1)*V*E
    const int*   __restrict__ ctx,    // [B][M][K]
    const float* __restrict__ p,      // [B][M] raw scores
    float* __restrict__ S_out,        // [B*M][E] row sums
    float* __restrict__ q,            // [B][E] atomic +=
    float* __restrict__ o1)           // [B][E] atomic += (if SAVE_O1)
{
    int blk = blockIdx.x;             // b*32 + s
    int b = blk >> 5, s = blk & 31;
    int t = threadIdx.x;
    int w = t >> 6, lane = t & 63;

    const float* row = p + (size_t)b*MM;
    float v[8];
    float mx = -INFINITY;
    #pragma unroll
    for (int i = 0; i < 8; i++) { v[i] = row[t + i*256]; mx = fmaxf(mx, v[i]); }
    __shared__ float red[6];
    #pragma unroll
    for (int off = 32; off; off >>= 1) mx = fmaxf(mx, __shfl_down(mx, off));
    if (lane == 0) red[w] = mx;
    __syncthreads();
    if (t == 0) red[4] = fmaxf(fmaxf(red[0],red[1]), fmaxf(red[2],red[3]));
    __syncthreads();
    mx = red[4];
    float sum = 0.f;
    #pragma unroll
    for (int i = 0; i < 8; i++) sum += __expf(v[i] - mx);
    #pragma unroll
    for (int off = 32; off; off >>= 1) sum += __shfl_down(sum, off);
    __syncthreads();
    if (lane == 0) red[w] = sum;
    __syncthreads();
    if (t == 0) red[5] = 1.f / (red[0]+red[1]+red[2]+red[3]);
    __syncthreads();
    float rs = red[5];

    int m0 = s*64 + w*16;
    float ax = 0.f, ay = 0.f;
    #pragma unroll 4
    for (int i = 0; i < 16; i++) {
        int m = m0 + i;
        float a = __expf(row[m] - mx) * rs;
        const int4 c = *(const int4*)(ctx + (size_t)(b*MM + m)*KK);
        float2 v0 = *(const float2*)(embT + (size_t)c.x*EE + lane*2);
        float2 v1 = *(const float2*)(embT + (size_t)c.y*EE + lane*2);
        float2 v2 = *(const float2*)(embT + (size_t)c.z*EE + lane*2);
        float2 v3 = *(const float2*)(embT + (size_t)c.w*EE + lane*2);
        float sx = v0.x + v1.x + v2.x + v3.x;
        float sy = v0.y + v1.y + v2.y + v3.y;
        *(float2*)(S_out + ((size_t)b*MM + m)*EE + lane*2) = make_float2(sx, sy);
        ax += a * sx;
        ay += a * sy;
    }
    __shared__ float acc_red[4][EE];
    acc_red[w][lane*2]   = ax;
    acc_red[w][lane*2+1] = ay;
    __syncthreads();
    if (t < EE) {
        float vv = acc_red[0][t] + acc_red[1][t] + acc_red[2][t] + acc_red[3][t];
        atomicAdd(&q[b*EE + t], vv);
        if (SAVE_O1) atomicAdd(&o1[b*EE + t], vv);
    }
}

// ---------------- streamed scores from S: p[b][m] = S[b][m].q[b] ----------------
__global__ __launch_bounds__(256) void scores_s_kernel(
    const float* __restrict__ S,      // [B*M][E]
    const float* __restrict__ q,      // [B][E]
    float* __restrict__ p)            // [B][M]
{
    int gid  = blockIdx.x * 4 + (threadIdx.x >> 6);
    int lane = threadIdx.x & 63;
    int b    = gid >> 11;
    float2 sv = *(const float2*)(S + (size_t)gid*EE + lane*2);
    float2 qv = *(const float2*)(q + b*EE + lane*2);
    float acc = sv.x*qv.x + sv.y*qv.y;
    #pragma unroll
    for (int off = 32; off; off >>= 1) acc += __shfl_down(acc, off);
    if (lane == 0) p[gid] = acc;
}

// ---------------- vocab logits GEMM + per-tile vocab-softmax partials ----------------
__global__ __launch_bounds__(256) void logits_kernel(
    const float* __restrict__ h,      // [B][G]
    const float* __restrict__ o1,     // [B][E]
    const float* __restrict__ Wv,     // [V][256]
    const float* __restrict__ bv,     // [V]
    float* __restrict__ logits,       // [B][V]
    float* __restrict__ part)         // [B][NT][2] = {max, sumexp} per tile
{
    __shared__ float Ut[256][32];
    __shared__ float Wt[32][132];
    int t = threadIdx.x;
    for (int i = t; i < 256*32; i += 256) {
        int e = i >> 5, b = i & 31;
        Ut[e][b] = (e < GG) ? h[b*GG + e] : o1[b*EE + (e - GG)];
    }
    int vg = t & 31;
    int bg = t >> 5;
    int v0 = blockIdx.x * 128;
    float acc[4][4];
    #pragma unroll
    for (int i = 0; i < 4; i++)
        #pragma unroll
        for (int j = 0; j < 4; j++) acc[i][j] = 0.f;

    int vrow = t >> 1;
    int half = t & 1;
    const float* wrow = Wv + (size_t)(v0 + vrow)*256 + half*16;
    bool vrok = (v0 + vrow) < VV;

    for (int ec = 0; ec < 256; ec += 32) {
        __syncthreads();
        #pragma unroll
        for (int j = 0; j < 4; j++) {
            float4 w = make_float4(0.f, 0.f, 0.f, 0.f);
            if (vrok) w = *(const float4*)(wrow + ec + j*4);
            int e0 = half*16 + j*4;
            Wt[e0+0][vrow] = w.x;
            Wt[e0+1][vrow] = w.y;
            Wt[e0+2][vrow] = w.z;
            Wt[e0+3][vrow] = w.w;
        }
        __syncthreads();
        #pragma unroll 8
        for (int e = 0; e < 32; e++) {
            float4 w = *(const float4*)(&Wt[e][vg*4]);
            float4 u = *(const float4*)(&Ut[ec + e][bg*4]);
            acc[0][0] += w.x*u.x; acc[0][1] += w.x*u.y; acc[0][2] += w.x*u.z; acc[0][3] += w.x*u.w;
            acc[1][0] += w.y*u.x; acc[1][1] += w.y*u.y; acc[1][2] += w.y*u.z; acc[1][3] += w.y*u.w;
            acc[2][0] += w.z*u.x; acc[2][1] += w.z*u.y; acc[2][2] += w.z*u.z; acc[2][3] += w.z*u.w;
            acc[3][0] += w.w*u.x; acc[3][1] += w.w*u.y; acc[3][2] += w.w*u.z; acc[3][3] += w.w*u.w;
        }
    }
    #pragma unroll
    for (int i = 0; i < 4; i++) {
        int v = v0 + vg*4 + i;
        bool ok = v < VV;
        float bb = ok ? bv[v] : 0.f;
        #pragma unroll
        for (int j = 0; j < 4; j++) {
            float val = ok ? (acc[i][j] + bb) : -INFINITY;
            acc[i][j] = val;
            if (ok) logits[(size_t)(bg*4 + j)*VV + v] = val;
        }
    }
    #pragma unroll
    for (int j = 0; j < 4; j++) {
        float m = fmaxf(fmaxf(acc[0][j], acc[1][j]), fmaxf(acc[2][j], acc[3][j]));
        #pragma unroll
        for (int off = 16; off; off >>= 1) m = fmaxf(m, __shfl_down(m, off, 32));
        m = __shfl(m, 0, 32);
        float s = 0.f;
        #pragma unroll
        for (int i = 0; i < 4; i++) s += __expf(acc[i][j] - m);
        #pragma unroll
        for (int off = 16; off; off >>= 1) s += __shfl_down(s, off, 32);
        if (vg == 0) {
            int b = bg*4 + j;
            part[((size_t)b*NT + blockIdx.x)*2]     = m;
            part[((size_t)b*NT + blockIdx.x)*2 + 1] = s;
        }
    }
}

// ---------------- fused tail: attn softmax (blocks 0..31) || vfinal (blocks 32..) ----
// Matched-footprint horizontal fusion (R10 lesson): both bodies 256 threads, <=2 KB
// LDS -> no occupancy penalty. Independent: softmax reads p2; vfinal reads logits+part.
__global__ __launch_bounds__(256) void tail_kernel(
    const float* __restrict__ p,      // [B][M] hop-2 scores
    float* __restrict__ attn,         // [B][M] out
    float* __restrict__ logits,       // [B][V] in-place normalize
    const float* __restrict__ part)   // [B][NT][2]
{
    int tid = threadIdx.x;
    __shared__ float redm[256], reds[256];
    __shared__ float statM[2], statR[2];
    if (blockIdx.x < BB) {
        // ---- softmax_m body ----
        int b = blockIdx.x;
        const float* row = p + (size_t)b*MM;
        float v[8];
        float mx = -INFINITY;
        #pragma unroll
        for (int i = 0; i < 8; i++) { v[i] = row[tid + i*256]; mx = fmaxf(mx, v[i]); }
        int w = tid >> 6, lane = tid & 63;
        #pragma unroll
        for (int off = 32; off; off >>= 1) mx = fmaxf(mx, __shfl_down(mx, off));
        if (lane == 0) redm[w] = mx;
        __syncthreads();
        if (tid == 0) redm[4] = fmaxf(fmaxf(redm[0],redm[1]), fmaxf(redm[2],redm[3]));
        __syncthreads();
        mx = redm[4];
        float sum = 0.f;
        #pragma unroll
        for (int i = 0; i < 8; i++) { v[i] = __expf(v[i] - mx); sum += v[i]; }
        #pragma unroll
        for (int off = 32; off; off >>= 1) sum += __shfl_down(sum, off);
        if (lane == 0) reds[w] = sum;
        __syncthreads();
        if (tid == 0) reds[4] = 1.f / (reds[0]+reds[1]+reds[2]+reds[3]);
        __syncthreads();
        float rs = reds[4];
        #pragma unroll
        for (int i = 0; i < 8; i++) attn[(size_t)b*MM + tid + i*256] = v[i]*rs;
        return;
    }
    // ---- vfinal body (block index re-based) ----
    int i0  = (blockIdx.x - BB)*256;
    int b0  = i0 / VV;
    int last = min(i0 + 255, BB*VV - 1);
    int bL  = last / VV;
    for (int pass = 0; pass < 2; pass++) {
        int b = b0 + pass;
        if (b > bL) break;
        float m = -INFINITY, s = 0.f;
        for (int tt = tid; tt < NT; tt += 256) {
            float pm = part[((size_t)b*NT + tt)*2];
            float ps = part[((size_t)b*NT + tt)*2 + 1];
            float M2 = fmaxf(m, pm);
            s = s*__expf(m - M2) + ps*__expf(pm - M2);
            m = M2;
        }
        redm[tid] = m; reds[tid] = s;
        __syncthreads();
        for (int off = 128; off; off >>= 1) {
            if (tid < off) {
                float m2 = redm[tid+off], s2 = reds[tid+off];
                float M2 = fmaxf(redm[tid], m2);
                reds[tid] = reds[tid]*__expf(redm[tid]-M2) + s2*__expf(m2-M2);
                redm[tid] = M2;
            }
            __syncthreads();
        }
        if (tid == 0) { statM[pass] = redm[0]; statR[pass] = 1.f / reds[0]; }
        __syncthreads();
    }
    int i = i0 + tid;
    if (i < BB*VV) {
        int b = i / VV;
        int pass = b - b0;
        logits[i] = __expf(logits[i] - statM[pass]) * statR[pass];
    }
}

extern "C" void kernel_launch(void* const* d_in, const int* in_sizes, int n_in,
                              void* d_out, int out_size, void* d_ws, size_t ws_size,
                              hipStream_t stream) {
    const int*   ctx    = (const int*)  d_in[0];
    const float* h_prev = (const float*)d_in[1];
    const int*   y      = (const int*)  d_in[2];
    const float* emb    = (const float*)d_in[3];
    const float* W_ih   = (const float*)d_in[4];
    const float* W_hh   = (const float*)d_in[5];
    const float* b_ih   = (const float*)d_in[6];
    const float* b_hh   = (const float*)d_in[7];
    const float* Wv     = (const float*)d_in[8];
    const float* bv     = (const float*)d_in[9];

    float* out_h    = (float*)d_out;                 // [B][G]
    float* out_pv   = out_h + BB*GG;                 // [B][V]
    float* out_attn = out_pv + (size_t)BB*VV;        // [B][M]

    float* ws   = (float*)d_ws;
    float* q    = ws;                       // 4096
    float* o1   = q + BB*EE;                // 4096
    float* p    = o1 + BB*EE;               // 65536
    float* tbuf = p + BB*MM;                // B*V (6.4 MB)
    float* S1   = tbuf + (size_t)BB*VV;     // 33.5 MB
    float* S2   = S1 + (size_t)BB*MM*EE;    // 33.5 MB
    float* part = S2 + (size_t)BB*MM*EE;    // B*NT*2 = 25024 floats

    const float* e0 = emb;
    const float* e1 = emb + (size_t)1*VV*EE;
    const float* e2 = emb + (size_t)2*VV*EE;

    // 1. GRU -> h, q ; zero o1
    gru_kernel<<<BB, 384, 0, stream>>>(emb, y, h_prev, W_ih, W_hh, b_ih, b_hh, out_h, q, o1);

    // 2-3. hop 0 scores via t-trick (table-0 stream + L2 lookup)
    t_kernel<<<NT, 256, 0, stream>>>(q, e0, tbuf);
    scores_lookup_kernel<<<(BB*MM)/256, 256, 0, stream>>>(tbuf, ctx, p);

    // 4. hop 0 memory read: gather table1 + write S1; q += o0, o1 = o0
    oacc_fused_kernel<1><<<BB*32, 256, 0, stream>>>(e1, ctx, p, S1, q, o1);

    // 5. vocab logits GEMM (h, o1 ready) + softmax partials
    logits_kernel<<<NT, 256, 0, stream>>>(out_h, o1, Wv, bv, out_pv, part);

    // 6. hop 1 streamed scores from S1
    scores_s_kernel<<<(BB*MM)/4, 256, 0, stream>>>(S1, q, p);

    // 7. hop 1 memory read: gather table2 + write S2; q += o
    oacc_fused_kernel<0><<<BB*32, 256, 0, stream>>>(e2, ctx, p, S2, q, nullptr);

    // 8. hop 2 streamed scores from S2
    scores_s_kernel<<<(BB*MM)/4, 256, 0, stream>>>(S2, q, p);

    // 9. fused tail: attn softmax || vocab softmax finalize
    tail_kernel<<<BB + VFB, 256, 0, stream>>>(p, out_attn, out_pv, part);
}

// Round 12
// 309.448 us; speedup vs baseline: 1.0679x; 1.0207x over previous
//
#include <hip/hip_runtime.h>
#include <math.h>

#define BB 32
#define MM 2048
#define KK 4
#define EE 128
#define GG 128
#define VV 50000
#define NT 391   // 128-row tiles over V
#define VFB 6250 // vfinal blocks: B*V/256

// ---------------- GRU cell: one block per batch row; also zeroes o1 ----------------
__global__ __launch_bounds__(384) void gru_kernel(
    const float* __restrict__ emb0,   // emb table 0 [V][E]
    const int*   __restrict__ y,      // [B]
    const float* __restrict__ hprev,  // [B][G]
    const float* __restrict__ W_ih,   // [3G][E]
    const float* __restrict__ W_hh,   // [3G][G]
    const float* __restrict__ b_ih,   // [3G]
    const float* __restrict__ b_hh,   // [3G]
    float* __restrict__ h_out,        // d_out [B][G]
    float* __restrict__ q,            // ws    [B][G]
    float* __restrict__ o1)           // ws    [B][E] -> zeroed (atomics later)
{
    int b = blockIdx.x;
    int t = threadIdx.x;
    __shared__ float x[EE], h[GG], gi[3*GG], gh[3*GG];
    if (t < EE)            x[t]       = emb0[(size_t)y[b]*EE + t];
    else if (t < 2*EE)     h[t-EE]    = hprev[b*GG + (t-EE)];
    if (t < EE) o1[b*EE + t] = 0.f;
    __syncthreads();
    {
        float accI = b_ih[t], accH = b_hh[t];
        const float* wi = W_ih + (size_t)t*EE;
        const float* wh = W_hh + (size_t)t*GG;
        #pragma unroll 8
        for (int e = 0; e < EE; e++) { accI += x[e]*wi[e]; accH += h[e]*wh[e]; }
        gi[t] = accI; gh[t] = accH;
    }
    __syncthreads();
    if (t < GG) {
        float r = 1.f/(1.f + __expf(-(gi[t]        + gh[t])));
        float z = 1.f/(1.f + __expf(-(gi[GG+t]     + gh[GG+t])));
        float n = tanhf(gi[2*GG+t] + r*gh[2*GG+t]);
        float hn = (1.f - z)*n + z*h[t];
        h_out[b*GG + t] = hn;
        q[b*GG + t]     = hn;
    }
}

// ---------------- t[b][v] = emb0[v] . q[b] : dense streaming GEMM (hop 0 scores) ----
__global__ __launch_bounds__(256) void t_kernel(
    const float* __restrict__ q,      // [B][E]
    const float* __restrict__ embT,   // [V][E]
    float* __restrict__ t)            // [B][V]
{
    __shared__ float Ut[EE][32];      // q transposed [e][b]
    __shared__ float Wt[32][132];     // [e_local][v_local], pad 128->132
    int tid = threadIdx.x;
    for (int i = tid; i < EE*32; i += 256) {
        int e = i >> 5, b = i & 31;
        Ut[e][b] = q[b*EE + e];
    }
    int vg = tid & 31;
    int bg = tid >> 5;
    int v0 = blockIdx.x * 128;
    float acc[4][4];
    #pragma unroll
    for (int i = 0; i < 4; i++)
        #pragma unroll
        for (int j = 0; j < 4; j++) acc[i][j] = 0.f;

    int vrow = tid >> 1;
    int half = tid & 1;
    const float* wrow = embT + (size_t)(v0 + vrow)*EE + half*16;
    bool vok = (v0 + vrow) < VV;

    for (int ec = 0; ec < EE; ec += 32) {
        __syncthreads();
        #pragma unroll
        for (int j = 0; j < 4; j++) {
            float4 w = make_float4(0.f, 0.f, 0.f, 0.f);
            if (vok) w = *(const float4*)(wrow + ec + j*4);
            int e0 = half*16 + j*4;
            Wt[e0+0][vrow] = w.x;
            Wt[e0+1][vrow] = w.y;
            Wt[e0+2][vrow] = w.z;
            Wt[e0+3][vrow] = w.w;
        }
        __syncthreads();
        #pragma unroll 8
        for (int e = 0; e < 32; e++) {
            float4 w = *(const float4*)(&Wt[e][vg*4]);
            float4 u = *(const float4*)(&Ut[ec + e][bg*4]);
            acc[0][0] += w.x*u.x; acc[0][1] += w.x*u.y; acc[0][2] += w.x*u.z; acc[0][3] += w.x*u.w;
            acc[1][0] += w.y*u.x; acc[1][1] += w.y*u.y; acc[1][2] += w.y*u.z; acc[1][3] += w.y*u.w;
            acc[2][0] += w.z*u.x; acc[2][1] += w.z*u.y; acc[2][2] += w.z*u.z; acc[2][3] += w.z*u.w;
            acc[3][0] += w.w*u.x; acc[3][1] += w.w*u.y; acc[3][2] += w.w*u.z; acc[3][3] += w.w*u.w;
        }
    }
    #pragma unroll
    for (int i = 0; i < 4; i++) {
        int v = v0 + vg*4 + i;
        if (v < VV) {
            #pragma unroll
            for (int j = 0; j < 4; j++)
                t[(size_t)(bg*4 + j)*VV + v] = acc[i][j];
        }
    }
}

// ---------------- hop 0 scores via t-lookup: p[b][m] = sum_k t[b][ctx] ----------------
__global__ __launch_bounds__(256) void scores_lookup_kernel(
    const float* __restrict__ t,      // [B][V]
    const int*   __restrict__ ctx,    // [B][M][K]
    float* __restrict__ p)            // [B][M]
{
    int gid = blockIdx.x*256 + threadIdx.x;   // == b*M + m
    int b   = gid >> 11;
    const int4 c = *(const int4*)(ctx + (size_t)gid*KK);
    const float* tb = t + (size_t)b*VV;
    p[gid] = tb[c.x] + tb[c.y] + tb[c.z] + tb[c.w];
}

// ---------------- fused: softmax stats + weighted gather + S write + q update ----------
// float4 gather (16B/lane, G13 sweet spot): 32 lanes cover a 512B row, so each wave
// processes 2 slots/iteration -> half the VMEM instructions of the float2 version,
// 2x row-level parallelism. Cross-half reduce via shfl_down(.,32) before LDS combine.
template<int SAVE_O1>
__global__ __launch_bounds__(256) void oacc_fused_kernel(
    const float* __restrict__ embT,   // emb + (hop+1)*V*E
    const int*   __restrict__ ctx,    // [B][M][K]
    const float* __restrict__ p,      // [B][M] raw scores
    float* __restrict__ S_out,        // [B*M][E] row sums
    float* __restrict__ q,            // [B][E] atomic +=
    float* __restrict__ o1)           // [B][E] atomic += (if SAVE_O1)
{
    int blk = blockIdx.x;             // b*32 + s
    int b = blk >> 5, s = blk & 31;
    int t = threadIdx.x;
    int w = t >> 6, lane = t & 63;
    int half = lane >> 5, sub = lane & 31;   // element group: e = sub*4

    // --- softmax stats over p[b][:] (all 2048), full-wave reduce (unchanged) ---
    const float* row = p + (size_t)b*MM;
    float v[8];
    float mx = -INFINITY;
    #pragma unroll
    for (int i = 0; i < 8; i++) { v[i] = row[t + i*256]; mx = fmaxf(mx, v[i]); }
    __shared__ float red[6];
    #pragma unroll
    for (int off = 32; off; off >>= 1) mx = fmaxf(mx, __shfl_down(mx, off));
    if (lane == 0) red[w] = mx;
    __syncthreads();
    if (t == 0) red[4] = fmaxf(fmaxf(red[0],red[1]), fmaxf(red[2],red[3]));
    __syncthreads();
    mx = red[4];
    float sum = 0.f;
    #pragma unroll
    for (int i = 0; i < 8; i++) sum += __expf(v[i] - mx);
    #pragma unroll
    for (int off = 32; off; off >>= 1) sum += __shfl_down(sum, off);
    __syncthreads();
    if (lane == 0) red[w] = sum;
    __syncthreads();
    if (t == 0) red[5] = 1.f / (red[0]+red[1]+red[2]+red[3]);
    __syncthreads();
    float rs = red[5];

    // --- float4 gather: wave w covers slots m0..m0+15, 2 per iteration ---
    int m0 = s*64 + w*16;
    float4 a4 = make_float4(0.f, 0.f, 0.f, 0.f);
    #pragma unroll 4
    for (int i = 0; i < 8; i++) {
        int m = m0 + i*2 + half;
        float a = __expf(row[m] - mx) * rs;
        const int4 c = *(const int4*)(ctx + (size_t)(b*MM + m)*KK);
        float4 v0 = *(const float4*)(embT + (size_t)c.x*EE + sub*4);
        float4 v1 = *(const float4*)(embT + (size_t)c.y*EE + sub*4);
        float4 v2 = *(const float4*)(embT + (size_t)c.z*EE + sub*4);
        float4 v3 = *(const float4*)(embT + (size_t)c.w*EE + sub*4);
        float4 sx;
        sx.x = v0.x + v1.x + v2.x + v3.x;
        sx.y = v0.y + v1.y + v2.y + v3.y;
        sx.z = v0.z + v1.z + v2.z + v3.z;
        sx.w = v0.w + v1.w + v2.w + v3.w;
        *(float4*)(S_out + ((size_t)b*MM + m)*EE + sub*4) = sx;
        a4.x += a * sx.x;
        a4.y += a * sx.y;
        a4.z += a * sx.z;
        a4.w += a * sx.w;
    }
    // cross-half reduce: lanes 0..31 accumulate lanes 32..63 (same element range)
    a4.x += __shfl_down(a4.x, 32);
    a4.y += __shfl_down(a4.y, 32);
    a4.z += __shfl_down(a4.z, 32);
    a4.w += __shfl_down(a4.w, 32);
    __shared__ float acc_red[4][EE];
    if (half == 0) *(float4*)(&acc_red[w][sub*4]) = a4;
    __syncthreads();
    if (t < EE) {
        float vv = acc_red[0][t] + acc_red[1][t] + acc_red[2][t] + acc_red[3][t];
        atomicAdd(&q[b*EE + t], vv);
        if (SAVE_O1) atomicAdd(&o1[b*EE + t], vv);
    }
}

// ---------------- streamed scores from S: p[b][m] = S[b][m].q[b] (float4, 8/block) ----
__global__ __launch_bounds__(256) void scores_s_kernel(
    const float* __restrict__ S,      // [B*M][E]
    const float* __restrict__ q,      // [B][E]
    float* __restrict__ p)            // [B][M]
{
    int wv = threadIdx.x >> 6, lane = threadIdx.x & 63;
    int half = lane >> 5, sub = lane & 31;
    int gid = blockIdx.x*8 + wv*2 + half;    // == b*M + m
    int b   = gid >> 11;
    float4 sv = *(const float4*)(S + (size_t)gid*EE + sub*4);
    float4 qv = *(const float4*)(q + b*EE + sub*4);
    float acc = sv.x*qv.x + sv.y*qv.y + sv.z*qv.z + sv.w*qv.w;
    #pragma unroll
    for (int off = 16; off; off >>= 1) acc += __shfl_down(acc, off, 32);
    if (sub == 0) p[gid] = acc;
}

// ---------------- vocab logits GEMM + per-tile vocab-softmax partials ----------------
__global__ __launch_bounds__(256) void logits_kernel(
    const float* __restrict__ h,      // [B][G]
    const float* __restrict__ o1,     // [B][E]
    const float* __restrict__ Wv,     // [V][256]
    const float* __restrict__ bv,     // [V]
    float* __restrict__ logits,       // [B][V]
    float* __restrict__ part)         // [B][NT][2] = {max, sumexp} per tile
{
    __shared__ float Ut[256][32];
    __shared__ float Wt[32][132];
    int t = threadIdx.x;
    for (int i = t; i < 256*32; i += 256) {
        int e = i >> 5, b = i & 31;
        Ut[e][b] = (e < GG) ? h[b*GG + e] : o1[b*EE + (e - GG)];
    }
    int vg = t & 31;
    int bg = t >> 5;
    int v0 = blockIdx.x * 128;
    float acc[4][4];
    #pragma unroll
    for (int i = 0; i < 4; i++)
        #pragma unroll
        for (int j = 0; j < 4; j++) acc[i][j] = 0.f;

    int vrow = t >> 1;
    int half = t & 1;
    const float* wrow = Wv + (size_t)(v0 + vrow)*256 + half*16;
    bool vrok = (v0 + vrow) < VV;

    for (int ec = 0; ec < 256; ec += 32) {
        __syncthreads();
        #pragma unroll
        for (int j = 0; j < 4; j++) {
            float4 w = make_float4(0.f, 0.f, 0.f, 0.f);
            if (vrok) w = *(const float4*)(wrow + ec + j*4);
            int e0 = half*16 + j*4;
            Wt[e0+0][vrow] = w.x;
            Wt[e0+1][vrow] = w.y;
            Wt[e0+2][vrow] = w.z;
            Wt[e0+3][vrow] = w.w;
        }
        __syncthreads();
        #pragma unroll 8
        for (int e = 0; e < 32; e++) {
            float4 w = *(const float4*)(&Wt[e][vg*4]);
            float4 u = *(const float4*)(&Ut[ec + e][bg*4]);
            acc[0][0] += w.x*u.x; acc[0][1] += w.x*u.y; acc[0][2] += w.x*u.z; acc[0][3] += w.x*u.w;
            acc[1][0] += w.y*u.x; acc[1][1] += w.y*u.y; acc[1][2] += w.y*u.z; acc[1][3] += w.y*u.w;
            acc[2][0] += w.z*u.x; acc[2][1] += w.z*u.y; acc[2][2] += w.z*u.z; acc[2][3] += w.z*u.w;
            acc[3][0] += w.w*u.x; acc[3][1] += w.w*u.y; acc[3][2] += w.w*u.z; acc[3][3] += w.w*u.w;
        }
    }
    #pragma unroll
    for (int i = 0; i < 4; i++) {
        int v = v0 + vg*4 + i;
        bool ok = v < VV;
        float bb = ok ? bv[v] : 0.f;
        #pragma unroll
        for (int j = 0; j < 4; j++) {
            float val = ok ? (acc[i][j] + bb) : -INFINITY;
            acc[i][j] = val;
            if (ok) logits[(size_t)(bg*4 + j)*VV + v] = val;
        }
    }
    #pragma unroll
    for (int j = 0; j < 4; j++) {
        float m = fmaxf(fmaxf(acc[0][j], acc[1][j]), fmaxf(acc[2][j], acc[3][j]));
        #pragma unroll
        for (int off = 16; off; off >>= 1) m = fmaxf(m, __shfl_down(m, off, 32));
        m = __shfl(m, 0, 32);
        float s = 0.f;
        #pragma unroll
        for (int i = 0; i < 4; i++) s += __expf(acc[i][j] - m);
        #pragma unroll
        for (int off = 16; off; off >>= 1) s += __shfl_down(s, off, 32);
        if (vg == 0) {
            int b = bg*4 + j;
            part[((size_t)b*NT + blockIdx.x)*2]     = m;
            part[((size_t)b*NT + blockIdx.x)*2 + 1] = s;
        }
    }
}

// ---------------- fused tail: attn softmax (blocks 0..31) || vfinal (blocks 32..) ----
__global__ __launch_bounds__(256) void tail_kernel(
    const float* __restrict__ p,      // [B][M] hop-2 scores
    float* __restrict__ attn,         // [B][M] out
    float* __restrict__ logits,       // [B][V] in-place normalize
    const float* __restrict__ part)   // [B][NT][2]
{
    int tid = threadIdx.x;
    __shared__ float redm[256], reds[256];
    __shared__ float statM[2], statR[2];
    if (blockIdx.x < BB) {
        // ---- softmax_m body ----
        int b = blockIdx.x;
        const float* row = p + (size_t)b*MM;
        float v[8];
        float mx = -INFINITY;
        #pragma unroll
        for (int i = 0; i < 8; i++) { v[i] = row[tid + i*256]; mx = fmaxf(mx, v[i]); }
        int w = tid >> 6, lane = tid & 63;
        #pragma unroll
        for (int off = 32; off; off >>= 1) mx = fmaxf(mx, __shfl_down(mx, off));
        if (lane == 0) redm[w] = mx;
        __syncthreads();
        if (tid == 0) redm[4] = fmaxf(fmaxf(redm[0],redm[1]), fmaxf(redm[2],redm[3]));
        __syncthreads();
        mx = redm[4];
        float sum = 0.f;
        #pragma unroll
        for (int i = 0; i < 8; i++) { v[i] = __expf(v[i] - mx); sum += v[i]; }
        #pragma unroll
        for (int off = 32; off; off >>= 1) sum += __shfl_down(sum, off);
        if (lane == 0) reds[w] = sum;
        __syncthreads();
        if (tid == 0) reds[4] = 1.f / (reds[0]+reds[1]+reds[2]+reds[3]);
        __syncthreads();
        float rs = reds[4];
        #pragma unroll
        for (int i = 0; i < 8; i++) attn[(size_t)b*MM + tid + i*256] = v[i]*rs;
        return;
    }
    // ---- vfinal body (block index re-based) ----
    int i0  = (blockIdx.x - BB)*256;
    int b0  = i0 / VV;
    int last = min(i0 + 255, BB*VV - 1);
    int bL  = last / VV;
    for (int pass = 0; pass < 2; pass++) {
        int b = b0 + pass;
        if (b > bL) break;
        float m = -INFINITY, s = 0.f;
        for (int tt = tid; tt < NT; tt += 256) {
            float pm = part[((size_t)b*NT + tt)*2];
            float ps = part[((size_t)b*NT + tt)*2 + 1];
            float M2 = fmaxf(m, pm);
            s = s*__expf(m - M2) + ps*__expf(pm - M2);
            m = M2;
        }
        redm[tid] = m; reds[tid] = s;
        __syncthreads();
        for (int off = 128; off; off >>= 1) {
            if (tid < off) {
                float m2 = redm[tid+off], s2 = reds[tid+off];
                float M2 = fmaxf(redm[tid], m2);
                reds[tid] = reds[tid]*__expf(redm[tid]-M2) + s2*__expf(m2-M2);
                redm[tid] = M2;
            }
            __syncthreads();
        }
        if (tid == 0) { statM[pass] = redm[0]; statR[pass] = 1.f / reds[0]; }
        __syncthreads();
    }
    int i = i0 + tid;
    if (i < BB*VV) {
        int b = i / VV;
        int pass = b - b0;
        logits[i] = __expf(logits[i] - statM[pass]) * statR[pass];
    }
}

extern "C" void kernel_launch(void* const* d_in, const int* in_sizes, int n_in,
                              void* d_out, int out_size, void* d_ws, size_t ws_size,
                              hipStream_t stream) {
    const int*   ctx    = (const int*)  d_in[0];
    const float* h_prev = (const float*)d_in[1];
    const int*   y      = (const int*)  d_in[2];
    const float* emb    = (const float*)d_in[3];
    const float* W_ih   = (const float*)d_in[4];
    const float* W_hh   = (const float*)d_in[5];
    const float* b_ih   = (const float*)d_in[6];
    const float* b_hh   = (const float*)d_in[7];
    const float* Wv     = (const float*)d_in[8];
    const float* bv     = (const float*)d_in[9];

    float* out_h    = (float*)d_out;                 // [B][G]
    float* out_pv   = out_h + BB*GG;                 // [B][V]
    float* out_attn = out_pv + (size_t)BB*VV;        // [B][M]

    float* ws   = (float*)d_ws;
    float* q    = ws;                       // 4096
    float* o1   = q + BB*EE;                // 4096
    float* p    = o1 + BB*EE;               // 65536
    float* tbuf = p + BB*MM;                // B*V (6.4 MB)
    float* S1   = tbuf + (size_t)BB*VV;     // 33.5 MB
    float* S2   = S1 + (size_t)BB*MM*EE;    // 33.5 MB
    float* part = S2 + (size_t)BB*MM*EE;    // B*NT*2 = 25024 floats

    const float* e0 = emb;
    const float* e1 = emb + (size_t)1*VV*EE;
    const float* e2 = emb + (size_t)2*VV*EE;

    // 1. GRU -> h, q ; zero o1
    gru_kernel<<<BB, 384, 0, stream>>>(emb, y, h_prev, W_ih, W_hh, b_ih, b_hh, out_h, q, o1);

    // 2-3. hop 0 scores via t-trick (table-0 stream + L2 lookup)
    t_kernel<<<NT, 256, 0, stream>>>(q, e0, tbuf);
    scores_lookup_kernel<<<(BB*MM)/256, 256, 0, stream>>>(tbuf, ctx, p);

    // 4. hop 0 memory read: gather table1 + write S1; q += o0, o1 = o0
    oacc_fused_kernel<1><<<BB*32, 256, 0, stream>>>(e1, ctx, p, S1, q, o1);

    // 5. vocab logits GEMM (h, o1 ready) + softmax partials
    logits_kernel<<<NT, 256, 0, stream>>>(out_h, o1, Wv, bv, out_pv, part);

    // 6. hop 1 streamed scores from S1
    scores_s_kernel<<<(BB*MM)/8, 256, 0, stream>>>(S1, q, p);

    // 7. hop 1 memory read: gather table2 + write S2; q += o
    oacc_fused_kernel<0><<<BB*32, 256, 0, stream>>>(e2, ctx, p, S2, q, nullptr);

    // 8. hop 2 streamed scores from S2
    scores_s_kernel<<<(BB*MM)/8, 256, 0, stream>>>(S2, q, p);

    // 9. fused tail: attn softmax || vocab softmax finalize
    tail_kernel<<<BB + VFB, 256, 0, stream>>>(p, out_attn, out_pv, part);
}